// Round 1
// baseline (1496.086 us; speedup 1.0000x reference)
//
#include <hip/hip_runtime.h>
#include <math.h>

#define NN 65536
#define NE 1048576
#define HH 128
#define GG 16
#define ELEC 32
#define BSZ 128
#define LL 63

__device__ __forceinline__ float dot4(const float4 a, const float4 b) {
    return fmaf(a.x, b.x, fmaf(a.y, b.y, fmaf(a.z, b.z, a.w * b.w)));
}
__device__ __forceinline__ float sigm(float x) { return 1.f / (1.f + __expf(-x)); }
__device__ __forceinline__ float tanh_fast(float x) { return 2.f / (1.f + __expf(-2.f * x)) - 1.f; }

// ---------------- setup kernels ----------------

__global__ void k_zero_int(int* __restrict__ p, int n) {
    int i = blockIdx.x * 256 + threadIdx.x;
    if (i < n) p[i] = 0;
}

__global__ void k_init_h(const float* __restrict__ x, float* __restrict__ h) {
    int i = blockIdx.x * 256 + threadIdx.x;   // over NN*HH
    int n = i >> 7, c = i & 127;
    h[i] = (c < 5) ? x[n * 5 + c] : 0.f;
}

__global__ void k_hist(const int* __restrict__ dst, int* __restrict__ deg) {
    int e = blockIdx.x * 256 + threadIdx.x;
    atomicAdd(&deg[dst[e]], 1);
}

// single block, 1024 threads, 64 elements each -> exclusive scan of deg into offs (+copy to cur)
__global__ void k_scan(const int* __restrict__ deg, int* __restrict__ offs, int* __restrict__ cur) {
    __shared__ int part[1024];
    int t = threadIdx.x;
    int base = t * 64;
    int s = 0;
    for (int i = 0; i < 64; ++i) s += deg[base + i];
    part[t] = s;
    __syncthreads();
    for (int d = 1; d < 1024; d <<= 1) {
        int v = (t >= d) ? part[t - d] : 0;
        __syncthreads();
        part[t] += v;
        __syncthreads();
    }
    int run = (t > 0) ? part[t - 1] : 0;
    for (int i = 0; i < 64; ++i) {
        int d0 = deg[base + i];
        offs[base + i] = run;
        cur[base + i] = run;
        run += d0;
    }
    if (t == 1023) offs[NN] = run;
}

__global__ void k_scatter(const int* __restrict__ src, const int* __restrict__ dst,
                          const float* __restrict__ ea, int* __restrict__ cur,
                          int* __restrict__ esrc, float* __restrict__ ew) {
    int e = blockIdx.x * 256 + threadIdx.x;
    int d = dst[e];
    int pos = atomicAdd(&cur[d], 1);
    esrc[pos] = src[e];
    ew[pos] = ea[e];
}

// ---------------- m = A(N,128) @ W(128,128) ----------------
// 256 threads: c = t&63 (owns cols c, c+64), ng = t>>6 (owns nodes ng*8..+7). 32 nodes/block.
__global__ __launch_bounds__(256) void k_gemm(const float* __restrict__ A,
        const float* __restrict__ W, float* __restrict__ C) {
    __shared__ float Wt[128 * 36];   // Wt[c][k] over BK=32 chunk, stride 36
    __shared__ float At[32 * 36];
    int t = threadIdx.x;
    int c = t & 63;
    int ng = t >> 6;
    int n0 = blockIdx.x * 32;
    float acc0[8] = {0,0,0,0,0,0,0,0};
    float acc1[8] = {0,0,0,0,0,0,0,0};
    for (int kc = 0; kc < 4; ++kc) {
        #pragma unroll
        for (int i = 0; i < 4; ++i) {
            int f = t + i * 256;             // 0..1023 float4s of the 32x128 chunk
            int k = f >> 5, c4 = f & 31;
            float4 v = *reinterpret_cast<const float4*>(W + (kc * 32 + k) * 128 + c4 * 4);
            Wt[(c4 * 4 + 0) * 36 + k] = v.x;
            Wt[(c4 * 4 + 1) * 36 + k] = v.y;
            Wt[(c4 * 4 + 2) * 36 + k] = v.z;
            Wt[(c4 * 4 + 3) * 36 + k] = v.w;
        }
        {
            int nloc = t >> 3, k4 = t & 7;
            float4 v = *reinterpret_cast<const float4*>(A + (size_t)(n0 + nloc) * 128 + kc * 32 + k4 * 4);
            *reinterpret_cast<float4*>(At + nloc * 36 + k4 * 4) = v;
        }
        __syncthreads();
        #pragma unroll
        for (int k4 = 0; k4 < 8; ++k4) {
            float4 wa = *reinterpret_cast<const float4*>(Wt + c * 36 + k4 * 4);
            float4 wb = *reinterpret_cast<const float4*>(Wt + (c + 64) * 36 + k4 * 4);
            #pragma unroll
            for (int j = 0; j < 8; ++j) {
                float4 hv = *reinterpret_cast<const float4*>(At + (ng * 8 + j) * 36 + k4 * 4);
                acc0[j] += dot4(wa, hv);
                acc1[j] += dot4(wb, hv);
            }
        }
        __syncthreads();
    }
    #pragma unroll
    for (int j = 0; j < 8; ++j) {
        int n = n0 + ng * 8 + j;
        C[(size_t)n * 128 + c] = acc0[j];
        C[(size_t)n * 128 + c + 64] = acc1[j];
    }
}

// ---------------- agg[n] = sum_{e: dst=n} ew[e] * m[esrc[e]] ----------------
// one wave per node; lane owns channels lane, lane+64
__global__ __launch_bounds__(256) void k_gather(const float* __restrict__ m,
        const int* __restrict__ offs, const int* __restrict__ esrc,
        const float* __restrict__ ew, float* __restrict__ agg) {
    int n = blockIdx.x * 4 + (threadIdx.x >> 6);
    int lane = threadIdx.x & 63;
    int k0 = offs[n], k1 = offs[n + 1];
    float a0 = 0.f, a1 = 0.f;
    for (int k = k0; k < k1; ++k) {
        int s = esrc[k];
        float w = ew[k];
        const float* row = m + (size_t)s * HH;
        a0 = fmaf(w, row[lane], a0);
        a1 = fmaf(w, row[lane + 64], a1);
    }
    agg[(size_t)n * HH + lane] = a0;
    agg[(size_t)n * HH + lane + 64] = a1;
}

// ---------------- fused GRU: h = GRU(agg, h), in place ----------------
// 256 threads: c = t&127, ng = t>>7; 16 nodes/block, 48 accumulators/thread
__global__ __launch_bounds__(256) void k_gru(float* __restrict__ h,
        const float* __restrict__ agg, const float* __restrict__ wih,
        const float* __restrict__ whh, const float* __restrict__ bih,
        const float* __restrict__ bhh) {
    __shared__ float wi[384 * 20];
    __shared__ float wh[384 * 20];
    __shared__ float ai[16 * 20];
    __shared__ float hi[16 * 20];
    int t = threadIdx.x;
    int c = t & 127;
    int ng = t >> 7;        // 0..1, owns 8 nodes
    int n0 = blockIdx.x * 16;
    float acc[6][8];
    #pragma unroll
    for (int q = 0; q < 6; ++q)
        #pragma unroll
        for (int j = 0; j < 8; ++j) acc[q][j] = 0.f;

    for (int kc = 0; kc < 8; ++kc) {   // BK = 16
        #pragma unroll
        for (int i = 0; i < 6; ++i) {
            int f = t + i * 256;        // 0..1535 float4s of the 384x16 chunk
            int j = f >> 2, kq = f & 3;
            float4 a = *reinterpret_cast<const float4*>(wih + j * 128 + kc * 16 + kq * 4);
            *reinterpret_cast<float4*>(wi + j * 20 + kq * 4) = a;
            float4 b = *reinterpret_cast<const float4*>(whh + j * 128 + kc * 16 + kq * 4);
            *reinterpret_cast<float4*>(wh + j * 20 + kq * 4) = b;
        }
        if (t < 64) {
            int nloc = t >> 2, kq = t & 3;
            *reinterpret_cast<float4*>(ai + nloc * 20 + kq * 4) =
                *reinterpret_cast<const float4*>(agg + (size_t)(n0 + nloc) * 128 + kc * 16 + kq * 4);
        } else if (t < 128) {
            int t2 = t - 64;
            int nloc = t2 >> 2, kq = t2 & 3;
            *reinterpret_cast<float4*>(hi + nloc * 20 + kq * 4) =
                *reinterpret_cast<const float4*>(h + (size_t)(n0 + nloc) * 128 + kc * 16 + kq * 4);
        }
        __syncthreads();
        #pragma unroll
        for (int k4 = 0; k4 < 4; ++k4) {
            float4 wir = *reinterpret_cast<const float4*>(wi + c * 20 + k4 * 4);
            float4 wiz = *reinterpret_cast<const float4*>(wi + (c + 128) * 20 + k4 * 4);
            float4 win = *reinterpret_cast<const float4*>(wi + (c + 256) * 20 + k4 * 4);
            float4 whr = *reinterpret_cast<const float4*>(wh + c * 20 + k4 * 4);
            float4 whz = *reinterpret_cast<const float4*>(wh + (c + 128) * 20 + k4 * 4);
            float4 whn = *reinterpret_cast<const float4*>(wh + (c + 256) * 20 + k4 * 4);
            #pragma unroll
            for (int j = 0; j < 8; ++j) {
                float4 av = *reinterpret_cast<const float4*>(ai + (ng * 8 + j) * 20 + k4 * 4);
                float4 hv = *reinterpret_cast<const float4*>(hi + (ng * 8 + j) * 20 + k4 * 4);
                acc[0][j] += dot4(wir, av);
                acc[1][j] += dot4(wiz, av);
                acc[2][j] += dot4(win, av);
                acc[3][j] += dot4(whr, hv);
                acc[4][j] += dot4(whz, hv);
                acc[5][j] += dot4(whn, hv);
            }
        }
        __syncthreads();
    }
    float bir = bih[c], biz = bih[c + 128], bin = bih[c + 256];
    float bhr = bhh[c], bhz = bhh[c + 128], bhn = bhh[c + 256];
    #pragma unroll
    for (int j = 0; j < 8; ++j) {
        int n = n0 + ng * 8 + j;
        float r = sigm(acc[0][j] + bir + acc[3][j] + bhr);
        float z = sigm(acc[1][j] + biz + acc[4][j] + bhz);
        float nv = tanh_fast(acc[2][j] + bin + r * (acc[5][j] + bhn));
        size_t idx = (size_t)n * 128 + c;
        float hold = h[idx];
        h[idx] = (1.f - z) * nv + z * hold;
    }
}

// ---------------- relu + rearrange + conv1d(stride2,k3) + relu ----------------
// block per (b,e): stage h[b, :, e, :] (16x128) in LDS, 63 outputs
__global__ __launch_bounds__(64) void k_conv(const float* __restrict__ h,
        const float* __restrict__ cw, const float* __restrict__ cb,
        float* __restrict__ co) {
    __shared__ float tile[16 * 128];
    __shared__ float w[48];
    int be = blockIdx.x;
    int b = be >> 5, e = be & 31;
    int t = threadIdx.x;
    if (t < 48) w[t] = cw[t];
    #pragma unroll
    for (int i = 0; i < 8; ++i) {
        int f = t + i * 64;             // 0..511 float4s
        int g = f >> 5, k4 = f & 31;
        float4 v = *reinterpret_cast<const float4*>(h + (size_t)(b * 512 + g * 32 + e) * 128 + k4 * 4);
        v.x = fmaxf(v.x, 0.f); v.y = fmaxf(v.y, 0.f);
        v.z = fmaxf(v.z, 0.f); v.w = fmaxf(v.w, 0.f);
        *reinterpret_cast<float4*>(tile + g * 128 + k4 * 4) = v;
    }
    __syncthreads();
    if (t < 63) {
        float s = cb[0];
        #pragma unroll
        for (int g = 0; g < 16; ++g) {
            const float* p = tile + g * 128 + 2 * t;
            s = fmaf(p[0], w[g * 3 + 0], s);
            s = fmaf(p[1], w[g * 3 + 1], s);
            s = fmaf(p[2], w[g * 3 + 2], s);
        }
        co[b * 2016 + e * 63 + t] = fmaxf(s, 0.f);
    }
}

// ---------------- lin1: (128, 2016) @ (128, 2016)^T + relu ----------------
__global__ __launch_bounds__(128) void k_lin1(const float* __restrict__ co,
        const float* __restrict__ w, const float* __restrict__ bias,
        float* __restrict__ fc1) {
    __shared__ float v[2016];
    int b = blockIdx.x, t = threadIdx.x;
    for (int i = t; i < 2016; i += 128) v[i] = co[b * 2016 + i];
    __syncthreads();
    float s = bias[t];
    const float* wr = w + t * 2016;
    for (int k = 0; k < 2016; k += 4) {
        float4 wv = *reinterpret_cast<const float4*>(wr + k);
        s = fmaf(wv.x, v[k + 0], s);
        s = fmaf(wv.y, v[k + 1], s);
        s = fmaf(wv.z, v[k + 2], s);
        s = fmaf(wv.w, v[k + 3], s);
    }
    fc1[b * 128 + t] = fmaxf(s, 0.f);
}

// ---------------- lin2 + softmax ----------------
__global__ __launch_bounds__(128) void k_lin2(const float* __restrict__ fc1,
        const float* __restrict__ w, const float* __restrict__ bias,
        float* __restrict__ out) {
    int b = threadIdx.x;   // 128 threads, 1 block
    float s0 = bias[0], s1 = bias[1], s2 = bias[2];
    const float* v = fc1 + b * 128;
    for (int k = 0; k < 128; ++k) {
        float x = v[k];
        s0 = fmaf(x, w[k], s0);
        s1 = fmaf(x, w[128 + k], s1);
        s2 = fmaf(x, w[256 + k], s2);
    }
    float mx = fmaxf(s0, fmaxf(s1, s2));
    float e0 = __expf(s0 - mx), e1 = __expf(s1 - mx), e2 = __expf(s2 - mx);
    float inv = 1.f / (e0 + e1 + e2);
    out[b * 3 + 0] = e0 * inv;
    out[b * 3 + 1] = e1 * inv;
    out[b * 3 + 2] = e2 * inv;
}

extern "C" void kernel_launch(void* const* d_in, const int* in_sizes, int n_in,
                              void* d_out, int out_size, void* d_ws, size_t ws_size,
                              hipStream_t stream) {
    const float* x   = (const float*)d_in[0];
    const int*   ei  = (const int*)d_in[1];
    const float* ea  = (const float*)d_in[2];
    // d_in[3] = bs (constant 128, unused)
    const float* gw  = (const float*)d_in[4];
    const float* wih = (const float*)d_in[5];
    const float* whh = (const float*)d_in[6];
    const float* bih = (const float*)d_in[7];
    const float* bhh = (const float*)d_in[8];
    const float* cw  = (const float*)d_in[9];
    const float* cb  = (const float*)d_in[10];
    const float* l1w = (const float*)d_in[11];
    const float* l1b = (const float*)d_in[12];
    const float* l2w = (const float*)d_in[13];
    const float* l2b = (const float*)d_in[14];
    float* out = (float*)d_out;

    // workspace layout (~107 MB)
    float* h   = (float*)d_ws;                  // NN*HH
    float* m   = h + (size_t)NN * HH;           // NN*HH
    float* agg = m + (size_t)NN * HH;           // NN*HH
    float* co  = agg + (size_t)NN * HH;         // BSZ*2016
    float* fc1 = co + (size_t)BSZ * 2016;       // BSZ*HH
    int*   deg  = (int*)(fc1 + (size_t)BSZ * HH);  // NN
    int*   offs = deg + NN;                     // NN+1
    int*   cur  = offs + (NN + 1);              // NN
    int*   esrc = cur + NN;                     // NE
    float* ew   = (float*)(esrc + NE);          // NE

    const int* src = ei;
    const int* dst = ei + NE;

    // CSC build (reused by both layers)
    k_zero_int<<<NN / 256, 256, 0, stream>>>(deg, NN);
    k_hist<<<NE / 256, 256, 0, stream>>>(dst, deg);
    k_scan<<<1, 1024, 0, stream>>>(deg, offs, cur);
    k_scatter<<<NE / 256, 256, 0, stream>>>(src, dst, ea, cur, esrc, ew);
    k_init_h<<<(NN * HH) / 256, 256, 0, stream>>>(x, h);

    for (int layer = 0; layer < 2; ++layer) {
        k_gemm<<<NN / 32, 256, 0, stream>>>(h, gw + (size_t)layer * HH * HH, m);
        k_gather<<<NN / 4, 256, 0, stream>>>(m, offs, esrc, ew, agg);
        k_gru<<<NN / 16, 256, 0, stream>>>(h, agg, wih, whh, bih, bhh);
    }

    k_conv<<<BSZ * ELEC, 64, 0, stream>>>(h, cw, cb, co);
    k_lin1<<<BSZ, 128, 0, stream>>>(co, l1w, l1b, fc1);
    k_lin2<<<1, 128, 0, stream>>>(fc1, l2w, l2b, out);
}

// Round 2
// 769.758 us; speedup vs baseline: 1.9436x; 1.9436x over previous
//
#include <hip/hip_runtime.h>
#include <math.h>

#define NN 65536
#define NE 1048576
#define HH 128
#define ELEC 32
#define BSZ 128

typedef unsigned short ushort_t;
typedef __bf16 bf16x8 __attribute__((ext_vector_type(8)));
typedef float f32x16 __attribute__((ext_vector_type(16)));

#define MFMA(A, B, C) __builtin_amdgcn_mfma_f32_32x32x16_bf16(A, B, C, 0, 0, 0)

__device__ __forceinline__ float sigm(float x) { return 1.f / (1.f + __expf(-x)); }
__device__ __forceinline__ float tanh_fast(float x) { return 2.f / (1.f + __expf(-2.f * x)) - 1.f; }

__device__ __forceinline__ float bf2f(ushort_t u) {
    union { unsigned int i; float f; } v; v.i = ((unsigned int)u) << 16; return v.f;
}
__device__ __forceinline__ ushort_t f2bf(float f) {
    union { float f; unsigned int i; } v; v.f = f;
    unsigned int r = (v.i + 0x7fffu + ((v.i >> 16) & 1u)) >> 16;
    return (ushort_t)r;
}

// ---------------- setup kernels ----------------

__global__ void k_zero_int(int* __restrict__ p, int n) {
    int i = blockIdx.x * 256 + threadIdx.x;
    if (i < n) p[i] = 0;
}

// h0 = pad(x) -> write bf16 hi/lo into xcat[:,128:256]
__global__ void k_init(const float* __restrict__ x, ushort_t* __restrict__ xh,
                       ushort_t* __restrict__ xl) {
    int i = blockIdx.x * 256 + threadIdx.x;   // n*128 + c
    int n = i >> 7, c = i & 127;
    float v = (c < 5) ? x[n * 5 + c] : 0.f;
    ushort_t hi = f2bf(v);
    size_t idx = (size_t)n * 256 + 128 + c;
    xh[idx] = hi;
    xl[idx] = f2bf(v - bf2f(hi));
}

__global__ void k_hist(const int* __restrict__ dst, int* __restrict__ deg) {
    int e = blockIdx.x * 256 + threadIdx.x;
    atomicAdd(&deg[dst[e]], 1);
}

__global__ void k_scan(const int* __restrict__ deg, int* __restrict__ offs, int* __restrict__ cur) {
    __shared__ int part[1024];
    int t = threadIdx.x;
    int base = t * 64;
    int s = 0;
    for (int i = 0; i < 64; ++i) s += deg[base + i];
    part[t] = s;
    __syncthreads();
    for (int d = 1; d < 1024; d <<= 1) {
        int v = (t >= d) ? part[t - d] : 0;
        __syncthreads();
        part[t] += v;
        __syncthreads();
    }
    int run = (t > 0) ? part[t - 1] : 0;
    for (int i = 0; i < 64; ++i) {
        int d0 = deg[base + i];
        offs[base + i] = run;
        cur[base + i] = run;
        run += d0;
    }
    if (t == 1023) offs[NN] = run;
}

__global__ void k_scatter(const int* __restrict__ src, const int* __restrict__ dst,
                          const float* __restrict__ ea, int* __restrict__ cur,
                          int* __restrict__ esrc, float* __restrict__ ew) {
    int e = blockIdx.x * 256 + threadIdx.x;
    int d = dst[e];
    int pos = atomicAdd(&cur[d], 1);
    esrc[pos] = src[e];
    ew[pos] = ea[e];
}

// ---------------- weight prep (bf16 hi/lo split) ----------------

// V[512][256]: rho = q*128 + g*32 + cc, c = q*32+cc
// g=0: rsum row ([wih_r | whh_r]); g=1: zsum; g=2: [wih_n | 0]; g=3: [0 | whh_n]
__global__ void k_prep_v(const float* __restrict__ wih, const float* __restrict__ whh,
                         ushort_t* __restrict__ vh, ushort_t* __restrict__ vl) {
    int i = blockIdx.x * 256 + threadIdx.x;   // rho*256 + k, 512 blocks
    int rho = i >> 8, k = i & 255;
    int q = rho >> 7, g = (rho >> 5) & 3, cc = rho & 31;
    int c = q * 32 + cc;
    float v;
    if (g == 0)      v = (k < 128) ? wih[c * 128 + k]          : whh[c * 128 + k - 128];
    else if (g == 1) v = (k < 128) ? wih[(128 + c) * 128 + k]  : whh[(128 + c) * 128 + k - 128];
    else if (g == 2) v = (k < 128) ? wih[(256 + c) * 128 + k]  : 0.f;
    else             v = (k < 128) ? 0.f                       : whh[(256 + c) * 128 + k - 128];
    ushort_t hi = f2bf(v);
    vh[i] = hi;
    vl[i] = f2bf(v - bf2f(hi));
}

// Gt[l][c][k] = gconv_w[l][k][c]
__global__ void k_prep_g(const float* __restrict__ gw, ushort_t* __restrict__ gh,
                         ushort_t* __restrict__ gl) {
    int i = blockIdx.x * 256 + threadIdx.x;   // l*16384 + c*128 + k, 128 blocks
    int l = i >> 14, r = i & 16383, c = r >> 7, k = r & 127;
    float v = gw[l * 16384 + k * 128 + c];
    ushort_t hi = f2bf(v);
    gh[i] = hi;
    gl[i] = f2bf(v - bf2f(hi));
}

// ---------------- m = h @ gw (MFMA, split bf16) ----------------
// block: 256 thr = 4 waves; wave q: 64 nodes (2 tiles of 32) x cols q*32..+31
__global__ __launch_bounds__(256, 2) void k_mgemm(const ushort_t* __restrict__ gth,
        const ushort_t* __restrict__ gtl, const ushort_t* __restrict__ xh,
        const ushort_t* __restrict__ xl, float* __restrict__ m) {
    __shared__ ushort_t lGh[128 * 136];
    __shared__ ushort_t lGl[128 * 136];
    int t = threadIdx.x;
    int lane = t & 63, q = t >> 6;
    int lr = lane & 31, lh = lane >> 5;
    int n0 = blockIdx.x * 64;
    #pragma unroll
    for (int i = 0; i < 8; ++i) {
        int f = t + i * 256;
        int row = f >> 4, jv = f & 15;
        *reinterpret_cast<uint4*>(lGh + row * 136 + jv * 8) =
            *reinterpret_cast<const uint4*>(gth + row * 128 + jv * 8);
        *reinterpret_cast<uint4*>(lGl + row * 136 + jv * 8) =
            *reinterpret_cast<const uint4*>(gtl + row * 128 + jv * 8);
    }
    __syncthreads();
    f32x16 a0, a1;
    #pragma unroll
    for (int r = 0; r < 16; ++r) { a0[r] = 0.f; a1[r] = 0.f; }
    size_t rowA0 = (size_t)(n0 + lr) * 256 + 128;
    size_t rowA1 = rowA0 + 32 * 256;
    #pragma unroll
    for (int ks = 0; ks < 8; ++ks) {
        int kg = ks * 16 + lh * 8;
        bf16x8 ah0 = *reinterpret_cast<const bf16x8*>(xh + rowA0 + kg);
        bf16x8 al0 = *reinterpret_cast<const bf16x8*>(xl + rowA0 + kg);
        bf16x8 ah1 = *reinterpret_cast<const bf16x8*>(xh + rowA1 + kg);
        bf16x8 al1 = *reinterpret_cast<const bf16x8*>(xl + rowA1 + kg);
        int boff = (q * 32 + lr) * 136 + ks * 16 + lh * 8;
        bf16x8 bh = *reinterpret_cast<const bf16x8*>(lGh + boff);
        bf16x8 bl = *reinterpret_cast<const bf16x8*>(lGl + boff);
        a0 = MFMA(ah0, bh, a0); a0 = MFMA(ah0, bl, a0); a0 = MFMA(al0, bh, a0);
        a1 = MFMA(ah1, bh, a1); a1 = MFMA(ah1, bl, a1); a1 = MFMA(al1, bh, a1);
    }
    int c = q * 32 + lr;
    #pragma unroll
    for (int r = 0; r < 16; ++r) {
        int row = (r & 3) + 8 * (r >> 2) + 4 * lh;
        m[(size_t)(n0 + row) * 128 + c] = a0[r];
        m[(size_t)(n0 + 32 + row) * 128 + c] = a1[r];
    }
}

// ---------------- agg[n] = sum ew * m[esrc] ; write bf16 hi/lo to xcat[:,0:128] ----------------
__global__ __launch_bounds__(256) void k_gather(const float* __restrict__ m,
        const int* __restrict__ offs, const int* __restrict__ esrc,
        const float* __restrict__ ew, ushort_t* __restrict__ xh, ushort_t* __restrict__ xl) {
    int n = blockIdx.x * 4 + (threadIdx.x >> 6);
    int lane = threadIdx.x & 63;
    int k0 = offs[n], k1 = offs[n + 1];
    float a0 = 0.f, a1 = 0.f;
    for (int k = k0; k < k1; ++k) {
        int s = esrc[k];
        float w = ew[k];
        const float* row = m + (size_t)s * HH;
        a0 = fmaf(w, row[lane], a0);
        a1 = fmaf(w, row[lane + 64], a1);
    }
    size_t i0 = (size_t)n * 256 + lane;
    ushort_t h0 = f2bf(a0);
    xh[i0] = h0; xl[i0] = f2bf(a0 - bf2f(h0));
    ushort_t h1 = f2bf(a1);
    xh[i0 + 64] = h1; xl[i0 + 64] = f2bf(a1 - bf2f(h1));
}

// ---------------- fused GRU via one K=256 MFMA GEMM ----------------
// block: 256 thr = 4 waves; wave q: 64 nodes x V-rows q*128..+127 (4 gate tiles)
__global__ __launch_bounds__(256, 2) void k_gru(const ushort_t* __restrict__ vh,
        const ushort_t* __restrict__ vl, ushort_t* __restrict__ xh, ushort_t* __restrict__ xl,
        const float* __restrict__ bih, const float* __restrict__ bhh) {
    __shared__ ushort_t lVh[512 * 40];
    __shared__ ushort_t lVl[512 * 40];
    int t = threadIdx.x;
    int lane = t & 63, q = t >> 6;
    int lr = lane & 31, lh = lane >> 5;
    int n0 = blockIdx.x * 64;
    f32x16 acc[2][4];
    #pragma unroll
    for (int nt = 0; nt < 2; ++nt)
        #pragma unroll
        for (int g = 0; g < 4; ++g)
            #pragma unroll
            for (int r = 0; r < 16; ++r) acc[nt][g][r] = 0.f;

    size_t rowA0 = (size_t)(n0 + lr) * 256;
    size_t rowA1 = rowA0 + 32 * 256;
    int kl = lh * 8;

    for (int kc = 0; kc < 8; ++kc) {          // 32-k chunks of K=256
        #pragma unroll
        for (int i = 0; i < 8; ++i) {
            int f = t + i * 256;
            int row = f >> 2, jv = f & 3;
            int src = row * 256 + kc * 32 + jv * 8;
            int dst = row * 40 + jv * 8;
            *reinterpret_cast<uint4*>(lVh + dst) = *reinterpret_cast<const uint4*>(vh + src);
            *reinterpret_cast<uint4*>(lVl + dst) = *reinterpret_cast<const uint4*>(vl + src);
        }
        __syncthreads();
        #pragma unroll
        for (int ks2 = 0; ks2 < 2; ++ks2) {
            int kg = kc * 32 + ks2 * 16 + kl;
            bf16x8 ah0 = *reinterpret_cast<const bf16x8*>(xh + rowA0 + kg);
            bf16x8 al0 = *reinterpret_cast<const bf16x8*>(xl + rowA0 + kg);
            bf16x8 ah1 = *reinterpret_cast<const bf16x8*>(xh + rowA1 + kg);
            bf16x8 al1 = *reinterpret_cast<const bf16x8*>(xl + rowA1 + kg);
            #pragma unroll
            for (int g = 0; g < 4; ++g) {
                int boff = (q * 128 + g * 32 + lr) * 40 + ks2 * 16 + kl;
                bf16x8 bh = *reinterpret_cast<const bf16x8*>(lVh + boff);
                bf16x8 bl = *reinterpret_cast<const bf16x8*>(lVl + boff);
                acc[0][g] = MFMA(ah0, bh, acc[0][g]);
                acc[0][g] = MFMA(ah0, bl, acc[0][g]);
                acc[0][g] = MFMA(al0, bh, acc[0][g]);
                acc[1][g] = MFMA(ah1, bh, acc[1][g]);
                acc[1][g] = MFMA(ah1, bl, acc[1][g]);
                acc[1][g] = MFMA(al1, bh, acc[1][g]);
            }
        }
        __syncthreads();   // also guards epilogue writes vs other waves' A-reads
    }

    int c = q * 32 + lr;
    float brz = bih[c] + bhh[c];
    float bzz = bih[128 + c] + bhh[128 + c];
    float bin = bih[256 + c];
    float bhn = bhh[256 + c];
    #pragma unroll
    for (int nt = 0; nt < 2; ++nt) {
        #pragma unroll
        for (int r = 0; r < 16; ++r) {
            int node = n0 + nt * 32 + (r & 3) + 8 * (r >> 2) + 4 * lh;
            float rg = sigm(acc[nt][0][r] + brz);
            float zg = sigm(acc[nt][1][r] + bzz);
            float nn = tanh_fast(acc[nt][2][r] + bin + rg * (acc[nt][3][r] + bhn));
            size_t idx = (size_t)node * 256 + 128 + c;
            float hold = bf2f(xh[idx]) + bf2f(xl[idx]);
            float hnew = (1.f - zg) * nn + zg * hold;
            ushort_t hi = f2bf(hnew);
            xh[idx] = hi;
            xl[idx] = f2bf(hnew - bf2f(hi));
        }
    }
}

// ---------------- relu + rearrange + conv1d(stride2,k3) + relu ----------------
__global__ __launch_bounds__(64) void k_conv(const ushort_t* __restrict__ xh,
        const ushort_t* __restrict__ xl, const float* __restrict__ cw,
        const float* __restrict__ cb, float* __restrict__ co) {
    __shared__ float tile[16 * 128];
    __shared__ float w[48];
    int be = blockIdx.x;
    int b = be >> 5, e = be & 31;
    int t = threadIdx.x;
    if (t < 48) w[t] = cw[t];
    #pragma unroll
    for (int i = 0; i < 8; ++i) {
        int f = t + i * 64;             // 0..511 groups of 4 channels
        int g = f >> 5, c4 = f & 31;
        size_t idx = (size_t)(b * 512 + g * 32 + e) * 256 + 128 + c4 * 4;
        ushort4 vh4 = *reinterpret_cast<const ushort4*>(xh + idx);
        ushort4 vl4 = *reinterpret_cast<const ushort4*>(xl + idx);
        float* dst = tile + g * 128 + c4 * 4;
        dst[0] = fmaxf(bf2f(vh4.x) + bf2f(vl4.x), 0.f);
        dst[1] = fmaxf(bf2f(vh4.y) + bf2f(vl4.y), 0.f);
        dst[2] = fmaxf(bf2f(vh4.z) + bf2f(vl4.z), 0.f);
        dst[3] = fmaxf(bf2f(vh4.w) + bf2f(vl4.w), 0.f);
    }
    __syncthreads();
    if (t < 63) {
        float s = cb[0];
        #pragma unroll
        for (int g = 0; g < 16; ++g) {
            const float* p = tile + g * 128 + 2 * t;
            s = fmaf(p[0], w[g * 3 + 0], s);
            s = fmaf(p[1], w[g * 3 + 1], s);
            s = fmaf(p[2], w[g * 3 + 2], s);
        }
        co[b * 2016 + e * 63 + t] = fmaxf(s, 0.f);
    }
}

// ---------------- lin1 ----------------
__global__ __launch_bounds__(128) void k_lin1(const float* __restrict__ co,
        const float* __restrict__ w, const float* __restrict__ bias,
        float* __restrict__ fc1) {
    __shared__ float v[2016];
    int b = blockIdx.x, t = threadIdx.x;
    for (int i = t; i < 2016; i += 128) v[i] = co[b * 2016 + i];
    __syncthreads();
    float s = bias[t];
    const float* wr = w + t * 2016;
    for (int k = 0; k < 2016; k += 4) {
        float4 wv = *reinterpret_cast<const float4*>(wr + k);
        s = fmaf(wv.x, v[k + 0], s);
        s = fmaf(wv.y, v[k + 1], s);
        s = fmaf(wv.z, v[k + 2], s);
        s = fmaf(wv.w, v[k + 3], s);
    }
    fc1[b * 128 + t] = fmaxf(s, 0.f);
}

// ---------------- lin2 + softmax ----------------
__global__ __launch_bounds__(128) void k_lin2(const float* __restrict__ fc1,
        const float* __restrict__ w, const float* __restrict__ bias,
        float* __restrict__ out) {
    int b = threadIdx.x;
    float s0 = bias[0], s1 = bias[1], s2 = bias[2];
    const float* v = fc1 + b * 128;
    for (int k = 0; k < 128; ++k) {
        float x = v[k];
        s0 = fmaf(x, w[k], s0);
        s1 = fmaf(x, w[128 + k], s1);
        s2 = fmaf(x, w[256 + k], s2);
    }
    float mx = fmaxf(s0, fmaxf(s1, s2));
    float e0 = __expf(s0 - mx), e1 = __expf(s1 - mx), e2 = __expf(s2 - mx);
    float inv = 1.f / (e0 + e1 + e2);
    out[b * 3 + 0] = e0 * inv;
    out[b * 3 + 1] = e1 * inv;
    out[b * 3 + 2] = e2 * inv;
}

extern "C" void kernel_launch(void* const* d_in, const int* in_sizes, int n_in,
                              void* d_out, int out_size, void* d_ws, size_t ws_size,
                              hipStream_t stream) {
    const float* x   = (const float*)d_in[0];
    const int*   ei  = (const int*)d_in[1];
    const float* ea  = (const float*)d_in[2];
    const float* gw  = (const float*)d_in[4];
    const float* wih = (const float*)d_in[5];
    const float* whh = (const float*)d_in[6];
    const float* bih = (const float*)d_in[7];
    const float* bhh = (const float*)d_in[8];
    const float* cw  = (const float*)d_in[9];
    const float* cb  = (const float*)d_in[10];
    const float* l1w = (const float*)d_in[11];
    const float* l1b = (const float*)d_in[12];
    const float* l2w = (const float*)d_in[13];
    const float* l2b = (const float*)d_in[14];
    float* out = (float*)d_out;

    // workspace layout (16B-aligned chunks first), ~112 MB
    char* p = (char*)d_ws;
    ushort_t* xh  = (ushort_t*)p; p += (size_t)NN * 256 * 2;      // 33.5 MB
    ushort_t* xl  = (ushort_t*)p; p += (size_t)NN * 256 * 2;      // 33.5 MB
    ushort_t* vh  = (ushort_t*)p; p += 512 * 256 * 2;
    ushort_t* vl  = (ushort_t*)p; p += 512 * 256 * 2;
    ushort_t* gth = (ushort_t*)p; p += 2 * 128 * 128 * 2;
    ushort_t* gtl = (ushort_t*)p; p += 2 * 128 * 128 * 2;
    float* m   = (float*)p; p += (size_t)NN * HH * 4;             // 33.5 MB
    float* co  = (float*)p; p += (size_t)BSZ * 2016 * 4;
    float* fc1 = (float*)p; p += (size_t)BSZ * HH * 4;
    int* deg   = (int*)p; p += (size_t)NN * 4;
    int* offs  = (int*)p; p += (size_t)(NN + 1) * 4;
    int* cur   = (int*)p; p += (size_t)NN * 4;
    int* esrc  = (int*)p; p += (size_t)NE * 4;
    float* ew  = (float*)p;

    const int* src = ei;
    const int* dst = ei + NE;

    // weight prep + CSC build
    k_prep_v<<<512, 256, 0, stream>>>(wih, whh, vh, vl);
    k_prep_g<<<128, 256, 0, stream>>>(gw, gth, gtl);
    k_zero_int<<<NN / 256, 256, 0, stream>>>(deg, NN);
    k_hist<<<NE / 256, 256, 0, stream>>>(dst, deg);
    k_scan<<<1, 1024, 0, stream>>>(deg, offs, cur);
    k_scatter<<<NE / 256, 256, 0, stream>>>(src, dst, ea, cur, esrc, ew);
    k_init<<<(NN * 128) / 256, 256, 0, stream>>>(x, xh, xl);

    for (int layer = 0; layer < 2; ++layer) {
        k_mgemm<<<NN / 64, 256, 0, stream>>>(gth + (size_t)layer * 16384,
                                             gtl + (size_t)layer * 16384, xh, xl, m);
        k_gather<<<NN / 4, 256, 0, stream>>>(m, offs, esrc, ew, xh, xl);
        k_gru<<<NN / 64, 256, 0, stream>>>(vh, vl, xh, xl, bih, bhh);
    }

    k_conv<<<BSZ * ELEC, 64, 0, stream>>>(xh, xl, cw, cb, co);
    k_lin1<<<BSZ, 128, 0, stream>>>(co, l1w, l1b, fc1);
    k_lin2<<<1, 128, 0, stream>>>(fc1, l2w, l2b, out);
}

// Round 3
// 668.790 us; speedup vs baseline: 2.2370x; 1.1510x over previous
//
#include <hip/hip_runtime.h>
#include <math.h>

#define NN 65536
#define NE 1048576
#define HH 128
#define ELEC 32
#define BSZ 128

typedef unsigned short ushort_t;
typedef __bf16 bf16x8 __attribute__((ext_vector_type(8)));
typedef float f32x16 __attribute__((ext_vector_type(16)));

#define MFMA(A, B, C) __builtin_amdgcn_mfma_f32_32x32x16_bf16(A, B, C, 0, 0, 0)

__device__ __forceinline__ float sigm(float x) { return 1.f / (1.f + __expf(-x)); }
__device__ __forceinline__ float tanh_fast(float x) { return 2.f / (1.f + __expf(-2.f * x)) - 1.f; }

__device__ __forceinline__ float bf2f(ushort_t u) {
    union { unsigned int i; float f; } v; v.i = ((unsigned int)u) << 16; return v.f;
}
__device__ __forceinline__ ushort_t f2bf(float f) {
    union { float f; unsigned int i; } v; v.f = f;
    unsigned int r = (v.i + 0x7fffu + ((v.i >> 16) & 1u)) >> 16;
    return (ushort_t)r;
}

// ---------------- setup kernels ----------------

__global__ void k_zero_int(int* __restrict__ p, int n) {
    int i = blockIdx.x * 256 + threadIdx.x;
    if (i < n) p[i] = 0;
}

// h0 = pad(x) -> bf16 hi/lo into xcat[:,128:256]
__global__ void k_init(const float* __restrict__ x, ushort_t* __restrict__ xh,
                       ushort_t* __restrict__ xl) {
    int i = blockIdx.x * 256 + threadIdx.x;   // n*128 + c
    int n = i >> 7, c = i & 127;
    float v = (c < 5) ? x[n * 5 + c] : 0.f;
    ushort_t hi = f2bf(v);
    size_t idx = (size_t)n * 256 + 128 + c;
    xh[idx] = hi;
    xl[idx] = f2bf(v - bf2f(hi));
}

__global__ void k_hist(const int* __restrict__ dst, int* __restrict__ deg) {
    int e = blockIdx.x * 256 + threadIdx.x;
    atomicAdd(&deg[dst[e]], 1);
}

// coalesced 3-phase exclusive scan of deg[NN] -> offs, cur
__global__ void k_scan1(const int* __restrict__ deg, int* __restrict__ bsum) {
    __shared__ int s[256];
    int b = blockIdx.x, t = threadIdx.x;
    s[t] = deg[b * 256 + t];
    __syncthreads();
    for (int d = 128; d > 0; d >>= 1) {
        if (t < d) s[t] += s[t + d];
        __syncthreads();
    }
    if (t == 0) bsum[b] = s[0];
}

__global__ void k_scan2(const int* __restrict__ bsum, int* __restrict__ boff,
                        int* __restrict__ offs) {
    __shared__ int s[256];
    int t = threadIdx.x;
    int v = bsum[t];
    s[t] = v;
    __syncthreads();
    for (int d = 1; d < 256; d <<= 1) {
        int u = (t >= d) ? s[t - d] : 0;
        __syncthreads();
        s[t] += u;
        __syncthreads();
    }
    boff[t] = s[t] - v;
    if (t == 255) offs[NN] = s[t];
}

__global__ void k_scan3(const int* __restrict__ deg, const int* __restrict__ boff,
                        int* __restrict__ offs, int* __restrict__ cur) {
    __shared__ int s[256];
    int b = blockIdx.x, t = threadIdx.x;
    int d0 = deg[b * 256 + t];
    s[t] = d0;
    __syncthreads();
    for (int d = 1; d < 256; d <<= 1) {
        int u = (t >= d) ? s[t - d] : 0;
        __syncthreads();
        s[t] += u;
        __syncthreads();
    }
    int ex = s[t] - d0 + boff[b];
    offs[b * 256 + t] = ex;
    cur[b * 256 + t] = ex;
}

__global__ void k_scatter(const int* __restrict__ src, const int* __restrict__ dst,
                          const float* __restrict__ ea, int* __restrict__ cur,
                          int* __restrict__ esrc, float* __restrict__ ew) {
    int e = blockIdx.x * 256 + threadIdx.x;
    int d = dst[e];
    int pos = atomicAdd(&cur[d], 1);
    esrc[pos] = src[e];
    ew[pos] = ea[e];
}

// ---------------- weight prep (bf16 hi/lo split) ----------------

// V[512][256]: rho = q*128 + g*32 + cc, c = q*32+cc
// g=0: [wih_r | whh_r]; g=1: [wih_z | whh_z]; g=2: [wih_n | 0]; g=3: [0 | whh_n]
__global__ void k_prep_v(const float* __restrict__ wih, const float* __restrict__ whh,
                         ushort_t* __restrict__ vh, ushort_t* __restrict__ vl) {
    int i = blockIdx.x * 256 + threadIdx.x;   // rho*256 + k, 512 blocks
    int rho = i >> 8, k = i & 255;
    int q = rho >> 7, g = (rho >> 5) & 3, cc = rho & 31;
    int c = q * 32 + cc;
    float v;
    if (g == 0)      v = (k < 128) ? wih[c * 128 + k]          : whh[c * 128 + k - 128];
    else if (g == 1) v = (k < 128) ? wih[(128 + c) * 128 + k]  : whh[(128 + c) * 128 + k - 128];
    else if (g == 2) v = (k < 128) ? wih[(256 + c) * 128 + k]  : 0.f;
    else             v = (k < 128) ? 0.f                       : whh[(256 + c) * 128 + k - 128];
    ushort_t hi = f2bf(v);
    vh[i] = hi;
    vl[i] = f2bf(v - bf2f(hi));
}

// Gt[l][c][k] = gconv_w[l][k][c]
__global__ void k_prep_g(const float* __restrict__ gw, ushort_t* __restrict__ gh,
                         ushort_t* __restrict__ gl) {
    int i = blockIdx.x * 256 + threadIdx.x;   // l*16384 + c*128 + k, 128 blocks
    int l = i >> 14, r = i & 16383, c = r >> 7, k = r & 127;
    float v = gw[l * 16384 + k * 128 + c];
    ushort_t hi = f2bf(v);
    gh[i] = hi;
    gl[i] = f2bf(v - bf2f(hi));
}

// ---------------- m = h @ gw (MFMA, split bf16, LDS-free) ----------------
// 2048 waves; wave w: nodes (w>>1)*64..+63, cols (w&1)*64..+63
__global__ __launch_bounds__(256, 2) void k_mgemm(const ushort_t* __restrict__ gth,
        const ushort_t* __restrict__ gtl, const ushort_t* __restrict__ xh,
        const ushort_t* __restrict__ xl, float* __restrict__ m) {
    int t = threadIdx.x;
    int lane = t & 63, q = t >> 6;
    int w = blockIdx.x * 4 + q;
    int n0 = (w >> 1) * 64;
    int c0 = (w & 1) * 64;
    int lr = lane & 31, lh = lane >> 5;
    f32x16 acc[2][2];
    #pragma unroll
    for (int nt = 0; nt < 2; ++nt)
        #pragma unroll
        for (int ct = 0; ct < 2; ++ct)
            #pragma unroll
            for (int r = 0; r < 16; ++r) acc[nt][ct][r] = 0.f;
    size_t rowA0 = (size_t)(n0 + lr) * 256 + 128;   // h region
    size_t rowA1 = rowA0 + 32 * 256;
    #pragma unroll
    for (int ks = 0; ks < 8; ++ks) {
        int kg = ks * 16 + lh * 8;
        bf16x8 ah0 = *reinterpret_cast<const bf16x8*>(xh + rowA0 + kg);
        bf16x8 al0 = *reinterpret_cast<const bf16x8*>(xl + rowA0 + kg);
        bf16x8 ah1 = *reinterpret_cast<const bf16x8*>(xh + rowA1 + kg);
        bf16x8 al1 = *reinterpret_cast<const bf16x8*>(xl + rowA1 + kg);
        #pragma unroll
        for (int ct = 0; ct < 2; ++ct) {
            int boff = (c0 + ct * 32 + lr) * 128 + kg;
            bf16x8 bh = *reinterpret_cast<const bf16x8*>(gth + boff);
            bf16x8 bl = *reinterpret_cast<const bf16x8*>(gtl + boff);
            acc[0][ct] = MFMA(ah0, bh, acc[0][ct]);
            acc[0][ct] = MFMA(ah0, bl, acc[0][ct]);
            acc[0][ct] = MFMA(al0, bh, acc[0][ct]);
            acc[1][ct] = MFMA(ah1, bh, acc[1][ct]);
            acc[1][ct] = MFMA(ah1, bl, acc[1][ct]);
            acc[1][ct] = MFMA(al1, bh, acc[1][ct]);
        }
    }
    #pragma unroll
    for (int nt = 0; nt < 2; ++nt)
        #pragma unroll
        for (int ct = 0; ct < 2; ++ct)
            #pragma unroll
            for (int r = 0; r < 16; ++r) {
                int row = (r & 3) + 8 * (r >> 2) + 4 * lh;
                m[(size_t)(n0 + nt * 32 + row) * 128 + c0 + ct * 32 + lr] = acc[nt][ct][r];
            }
}

// ---------------- agg[n] = sum ew * m[esrc] ; bf16 hi/lo into xcat[:,0:128] ----------------
__global__ __launch_bounds__(256) void k_gather(const float* __restrict__ m,
        const int* __restrict__ offs, const int* __restrict__ esrc,
        const float* __restrict__ ew, ushort_t* __restrict__ xh, ushort_t* __restrict__ xl) {
    int n = blockIdx.x * 4 + (threadIdx.x >> 6);
    int lane = threadIdx.x & 63;
    int k0 = offs[n], k1 = offs[n + 1];
    float a0 = 0.f, a1 = 0.f;
    int k = k0;
    for (; k < k1 && (k & 3); ++k) {
        int s = esrc[k];
        float w = ew[k];
        const float* row = m + (size_t)s * HH;
        a0 = fmaf(w, row[lane], a0);
        a1 = fmaf(w, row[lane + 64], a1);
    }
    for (; k + 4 <= k1; k += 4) {
        int4 s4 = *reinterpret_cast<const int4*>(esrc + k);
        float4 w4 = *reinterpret_cast<const float4*>(ew + k);
        const float* r0 = m + (size_t)s4.x * HH;
        const float* r1 = m + (size_t)s4.y * HH;
        const float* r2 = m + (size_t)s4.z * HH;
        const float* r3 = m + (size_t)s4.w * HH;
        float v0a = r0[lane], v0b = r0[lane + 64];
        float v1a = r1[lane], v1b = r1[lane + 64];
        float v2a = r2[lane], v2b = r2[lane + 64];
        float v3a = r3[lane], v3b = r3[lane + 64];
        a0 = fmaf(w4.x, v0a, a0); a1 = fmaf(w4.x, v0b, a1);
        a0 = fmaf(w4.y, v1a, a0); a1 = fmaf(w4.y, v1b, a1);
        a0 = fmaf(w4.z, v2a, a0); a1 = fmaf(w4.z, v2b, a1);
        a0 = fmaf(w4.w, v3a, a0); a1 = fmaf(w4.w, v3b, a1);
    }
    for (; k < k1; ++k) {
        int s = esrc[k];
        float w = ew[k];
        const float* row = m + (size_t)s * HH;
        a0 = fmaf(w, row[lane], a0);
        a1 = fmaf(w, row[lane + 64], a1);
    }
    size_t i0 = (size_t)n * 256 + lane;
    ushort_t h0 = f2bf(a0);
    xh[i0] = h0; xl[i0] = f2bf(a0 - bf2f(h0));
    ushort_t h1 = f2bf(a1);
    xh[i0 + 64] = h1; xl[i0 + 64] = f2bf(a1 - bf2f(h1));
}

// ---------------- fused GRU via one K=256 MFMA GEMM (LDS-free) ----------------
// wave q: 64 nodes x V-rows q*128..+127 (4 gate tiles of 32 channels)
__global__ __launch_bounds__(256, 2) void k_gru(const ushort_t* __restrict__ vh,
        const ushort_t* __restrict__ vl, ushort_t* __restrict__ xh, ushort_t* __restrict__ xl,
        const float* __restrict__ bih, const float* __restrict__ bhh) {
    int t = threadIdx.x;
    int lane = t & 63, q = t >> 6;
    int lr = lane & 31, lh = lane >> 5;
    int n0 = blockIdx.x * 64;
    f32x16 acc[2][4];
    #pragma unroll
    for (int nt = 0; nt < 2; ++nt)
        #pragma unroll
        for (int g = 0; g < 4; ++g)
            #pragma unroll
            for (int r = 0; r < 16; ++r) acc[nt][g][r] = 0.f;

    size_t rowA0 = (size_t)(n0 + lr) * 256;
    size_t rowA1 = rowA0 + 32 * 256;
    #pragma unroll
    for (int ks = 0; ks < 16; ++ks) {
        int kg = ks * 16 + lh * 8;
        bf16x8 ah0 = *reinterpret_cast<const bf16x8*>(xh + rowA0 + kg);
        bf16x8 al0 = *reinterpret_cast<const bf16x8*>(xl + rowA0 + kg);
        bf16x8 ah1 = *reinterpret_cast<const bf16x8*>(xh + rowA1 + kg);
        bf16x8 al1 = *reinterpret_cast<const bf16x8*>(xl + rowA1 + kg);
        #pragma unroll
        for (int g = 0; g < 4; ++g) {
            int boff = (q * 128 + g * 32 + lr) * 256 + kg;
            bf16x8 bh = *reinterpret_cast<const bf16x8*>(vh + boff);
            bf16x8 bl = *reinterpret_cast<const bf16x8*>(vl + boff);
            acc[0][g] = MFMA(ah0, bh, acc[0][g]);
            acc[0][g] = MFMA(ah0, bl, acc[0][g]);
            acc[0][g] = MFMA(al0, bh, acc[0][g]);
            acc[1][g] = MFMA(ah1, bh, acc[1][g]);
            acc[1][g] = MFMA(ah1, bl, acc[1][g]);
            acc[1][g] = MFMA(al1, bh, acc[1][g]);
        }
    }

    __syncthreads();   // all waves done reading h before in-place overwrite

    int c = q * 32 + lr;
    float brz = bih[c] + bhh[c];
    float bzz = bih[128 + c] + bhh[128 + c];
    float bin = bih[256 + c];
    float bhn = bhh[256 + c];
    #pragma unroll
    for (int nt = 0; nt < 2; ++nt) {
        #pragma unroll
        for (int r = 0; r < 16; ++r) {
            int node = n0 + nt * 32 + (r & 3) + 8 * (r >> 2) + 4 * lh;
            float rg = sigm(acc[nt][0][r] + brz);
            float zg = sigm(acc[nt][1][r] + bzz);
            float nn = tanh_fast(acc[nt][2][r] + bin + rg * (acc[nt][3][r] + bhn));
            size_t idx = (size_t)node * 256 + 128 + c;
            float hold = bf2f(xh[idx]) + bf2f(xl[idx]);
            float hnew = (1.f - zg) * nn + zg * hold;
            ushort_t hi = f2bf(hnew);
            xh[idx] = hi;
            xl[idx] = f2bf(hnew - bf2f(hi));
        }
    }
}

// ---------------- relu + rearrange + conv1d(stride2,k3) + relu ----------------
__global__ __launch_bounds__(64) void k_conv(const ushort_t* __restrict__ xh,
        const ushort_t* __restrict__ xl, const float* __restrict__ cw,
        const float* __restrict__ cb, float* __restrict__ co) {
    __shared__ float tile[16 * 128];
    __shared__ float w[48];
    int be = blockIdx.x;
    int b = be >> 5, e = be & 31;
    int t = threadIdx.x;
    if (t < 48) w[t] = cw[t];
    #pragma unroll
    for (int i = 0; i < 8; ++i) {
        int f = t + i * 64;             // 0..511 groups of 4 channels
        int g = f >> 5, c4 = f & 31;
        size_t idx = (size_t)(b * 512 + g * 32 + e) * 256 + 128 + c4 * 4;
        ushort4 vh4 = *reinterpret_cast<const ushort4*>(xh + idx);
        ushort4 vl4 = *reinterpret_cast<const ushort4*>(xl + idx);
        float* dst = tile + g * 128 + c4 * 4;
        dst[0] = fmaxf(bf2f(vh4.x) + bf2f(vl4.x), 0.f);
        dst[1] = fmaxf(bf2f(vh4.y) + bf2f(vl4.y), 0.f);
        dst[2] = fmaxf(bf2f(vh4.z) + bf2f(vl4.z), 0.f);
        dst[3] = fmaxf(bf2f(vh4.w) + bf2f(vl4.w), 0.f);
    }
    __syncthreads();
    if (t < 63) {
        float s = cb[0];
        #pragma unroll
        for (int g = 0; g < 16; ++g) {
            const float* p = tile + g * 128 + 2 * t;
            s = fmaf(p[0], w[g * 3 + 0], s);
            s = fmaf(p[1], w[g * 3 + 1], s);
            s = fmaf(p[2], w[g * 3 + 2], s);
        }
        co[b * 2016 + e * 63 + t] = fmaxf(s, 0.f);
    }
}

// ---------------- lin1 ----------------
__global__ __launch_bounds__(128) void k_lin1(const float* __restrict__ co,
        const float* __restrict__ w, const float* __restrict__ bias,
        float* __restrict__ fc1) {
    __shared__ float v[2016];
    int b = blockIdx.x, t = threadIdx.x;
    for (int i = t; i < 2016; i += 128) v[i] = co[b * 2016 + i];
    __syncthreads();
    float s = bias[t];
    const float* wr = w + t * 2016;
    for (int k = 0; k < 2016; k += 4) {
        float4 wv = *reinterpret_cast<const float4*>(wr + k);
        s = fmaf(wv.x, v[k + 0], s);
        s = fmaf(wv.y, v[k + 1], s);
        s = fmaf(wv.z, v[k + 2], s);
        s = fmaf(wv.w, v[k + 3], s);
    }
    fc1[b * 128 + t] = fmaxf(s, 0.f);
}

// ---------------- lin2 + softmax ----------------
__global__ __launch_bounds__(128) void k_lin2(const float* __restrict__ fc1,
        const float* __restrict__ w, const float* __restrict__ bias,
        float* __restrict__ out) {
    int b = threadIdx.x;
    float s0 = bias[0], s1 = bias[1], s2 = bias[2];
    const float* v = fc1 + b * 128;
    for (int k = 0; k < 128; ++k) {
        float x = v[k];
        s0 = fmaf(x, w[k], s0);
        s1 = fmaf(x, w[128 + k], s1);
        s2 = fmaf(x, w[256 + k], s2);
    }
    float mx = fmaxf(s0, fmaxf(s1, s2));
    float e0 = __expf(s0 - mx), e1 = __expf(s1 - mx), e2 = __expf(s2 - mx);
    float inv = 1.f / (e0 + e1 + e2);
    out[b * 3 + 0] = e0 * inv;
    out[b * 3 + 1] = e1 * inv;
    out[b * 3 + 2] = e2 * inv;
}

extern "C" void kernel_launch(void* const* d_in, const int* in_sizes, int n_in,
                              void* d_out, int out_size, void* d_ws, size_t ws_size,
                              hipStream_t stream) {
    const float* x   = (const float*)d_in[0];
    const int*   ei  = (const int*)d_in[1];
    const float* ea  = (const float*)d_in[2];
    const float* gw  = (const float*)d_in[4];
    const float* wih = (const float*)d_in[5];
    const float* whh = (const float*)d_in[6];
    const float* bih = (const float*)d_in[7];
    const float* bhh = (const float*)d_in[8];
    const float* cw  = (const float*)d_in[9];
    const float* cb  = (const float*)d_in[10];
    const float* l1w = (const float*)d_in[11];
    const float* l1b = (const float*)d_in[12];
    const float* l2w = (const float*)d_in[13];
    const float* l2b = (const float*)d_in[14];
    float* out = (float*)d_out;

    char* p = (char*)d_ws;
    ushort_t* xh  = (ushort_t*)p; p += (size_t)NN * 256 * 2;
    ushort_t* xl  = (ushort_t*)p; p += (size_t)NN * 256 * 2;
    ushort_t* vh  = (ushort_t*)p; p += 512 * 256 * 2;
    ushort_t* vl  = (ushort_t*)p; p += 512 * 256 * 2;
    ushort_t* gth = (ushort_t*)p; p += 2 * 128 * 128 * 2;
    ushort_t* gtl = (ushort_t*)p; p += 2 * 128 * 128 * 2;
    float* m   = (float*)p; p += (size_t)NN * HH * 4;
    float* co  = (float*)p; p += (size_t)BSZ * 2016 * 4;
    float* fc1 = (float*)p; p += (size_t)BSZ * HH * 4;
    int* deg   = (int*)p; p += (size_t)NN * 4;
    int* offs  = (int*)p; p += (size_t)(NN + 1) * 4;
    int* cur   = (int*)p; p += (size_t)NN * 4;
    int* bsum  = (int*)p; p += 256 * 4;
    int* boff  = (int*)p; p += 256 * 4;
    int* esrc  = (int*)p; p += (size_t)NE * 4;
    float* ew  = (float*)p;

    const int* src = ei;
    const int* dst = ei + NE;

    k_prep_v<<<512, 256, 0, stream>>>(wih, whh, vh, vl);
    k_prep_g<<<128, 256, 0, stream>>>(gw, gth, gtl);
    k_zero_int<<<NN / 256, 256, 0, stream>>>(deg, NN);
    k_hist<<<NE / 256, 256, 0, stream>>>(dst, deg);
    k_scan1<<<256, 256, 0, stream>>>(deg, bsum);
    k_scan2<<<1, 256, 0, stream>>>(bsum, boff, offs);
    k_scan3<<<256, 256, 0, stream>>>(deg, boff, offs, cur);
    k_scatter<<<NE / 256, 256, 0, stream>>>(src, dst, ea, cur, esrc, ew);
    k_init<<<(NN * 128) / 256, 256, 0, stream>>>(x, xh, xl);

    for (int layer = 0; layer < 2; ++layer) {
        k_mgemm<<<512, 256, 0, stream>>>(gth + (size_t)layer * 16384,
                                         gtl + (size_t)layer * 16384, xh, xl, m);
        k_gather<<<NN / 4, 256, 0, stream>>>(m, offs, esrc, ew, xh, xl);
        k_gru<<<NN / 64, 256, 0, stream>>>(vh, vl, xh, xl, bih, bhh);
    }

    k_conv<<<BSZ * ELEC, 64, 0, stream>>>(xh, xl, cw, cb, co);
    k_lin1<<<BSZ, 128, 0, stream>>>(co, l1w, l1b, fc1);
    k_lin2<<<1, 128, 0, stream>>>(fc1, l2w, l2b, out);
}

// Round 4
// 509.809 us; speedup vs baseline: 2.9346x; 1.3118x over previous
//
#include <hip/hip_runtime.h>
#include <math.h>

#define NN 65536
#define NE 1048576
#define HH 128
#define ELEC 32
#define BSZ 128

typedef unsigned short ushort_t;
typedef __bf16 bf16x8 __attribute__((ext_vector_type(8)));
typedef float f32x16 __attribute__((ext_vector_type(16)));

#define MFMA(A, B, C) __builtin_amdgcn_mfma_f32_32x32x16_bf16(A, B, C, 0, 0, 0)

__device__ __forceinline__ float sigm(float x) { return 1.f / (1.f + __expf(-x)); }
__device__ __forceinline__ float tanh_fast(float x) { return 2.f / (1.f + __expf(-2.f * x)) - 1.f; }

__device__ __forceinline__ float bf2f(ushort_t u) {
    union { unsigned int i; float f; } v; v.i = ((unsigned int)u) << 16; return v.f;
}
__device__ __forceinline__ ushort_t f2bf(float f) {
    union { float f; unsigned int i; } v; v.f = f;
    unsigned int r = (v.i + 0x7fffu + ((v.i >> 16) & 1u)) >> 16;
    return (ushort_t)r;
}

// ---------------- setup kernels ----------------

__global__ void k_zero_int(int* __restrict__ p, int n) {
    int i = blockIdx.x * 256 + threadIdx.x;
    if (i < n) p[i] = 0;
}

// h0 = pad(x) -> bf16 into xcat[:,128:256]
__global__ void k_init(const float* __restrict__ x, ushort_t* __restrict__ xh) {
    int i = blockIdx.x * 256 + threadIdx.x;   // n*128 + c
    int n = i >> 7, c = i & 127;
    float v = (c < 5) ? x[n * 5 + c] : 0.f;
    xh[(size_t)n * 256 + 128 + c] = f2bf(v);
}

__global__ void k_hist(const int* __restrict__ dst, int* __restrict__ deg) {
    int e = blockIdx.x * 256 + threadIdx.x;
    atomicAdd(&deg[dst[e]], 1);
}

// coalesced 3-phase exclusive scan of deg[NN] -> offs, cur
__global__ void k_scan1(const int* __restrict__ deg, int* __restrict__ bsum) {
    __shared__ int s[256];
    int b = blockIdx.x, t = threadIdx.x;
    s[t] = deg[b * 256 + t];
    __syncthreads();
    for (int d = 128; d > 0; d >>= 1) {
        if (t < d) s[t] += s[t + d];
        __syncthreads();
    }
    if (t == 0) bsum[b] = s[0];
}

__global__ void k_scan2(const int* __restrict__ bsum, int* __restrict__ boff,
                        int* __restrict__ offs) {
    __shared__ int s[256];
    int t = threadIdx.x;
    int v = bsum[t];
    s[t] = v;
    __syncthreads();
    for (int d = 1; d < 256; d <<= 1) {
        int u = (t >= d) ? s[t - d] : 0;
        __syncthreads();
        s[t] += u;
        __syncthreads();
    }
    boff[t] = s[t] - v;
    if (t == 255) offs[NN] = s[t];
}

__global__ void k_scan3(const int* __restrict__ deg, const int* __restrict__ boff,
                        int* __restrict__ offs, int* __restrict__ cur) {
    __shared__ int s[256];
    int b = blockIdx.x, t = threadIdx.x;
    int d0 = deg[b * 256 + t];
    s[t] = d0;
    __syncthreads();
    for (int d = 1; d < 256; d <<= 1) {
        int u = (t >= d) ? s[t - d] : 0;
        __syncthreads();
        s[t] += u;
        __syncthreads();
    }
    int ex = s[t] - d0 + boff[b];
    offs[b * 256 + t] = ex;
    cur[b * 256 + t] = ex;
}

__global__ void k_scatter(const int* __restrict__ src, const int* __restrict__ dst,
                          const float* __restrict__ ea, int* __restrict__ cur,
                          int* __restrict__ esrc, float* __restrict__ ew) {
    int e = blockIdx.x * 256 + threadIdx.x;
    int d = dst[e];
    int pos = atomicAdd(&cur[d], 1);
    esrc[pos] = src[e];
    ew[pos] = ea[e];
}

// ---------------- weight prep (bf16) ----------------

// V[512][256]: rho = q*128 + g*32 + cc, c = q*32+cc
__global__ void k_prep_v(const float* __restrict__ wih, const float* __restrict__ whh,
                         ushort_t* __restrict__ vh) {
    int i = blockIdx.x * 256 + threadIdx.x;   // rho*256 + k, 512 blocks
    int rho = i >> 8, k = i & 255;
    int q = rho >> 7, g = (rho >> 5) & 3, cc = rho & 31;
    int c = q * 32 + cc;
    float v;
    if (g == 0)      v = (k < 128) ? wih[c * 128 + k]          : whh[c * 128 + k - 128];
    else if (g == 1) v = (k < 128) ? wih[(128 + c) * 128 + k]  : whh[(128 + c) * 128 + k - 128];
    else if (g == 2) v = (k < 128) ? wih[(256 + c) * 128 + k]  : 0.f;
    else             v = (k < 128) ? 0.f                       : whh[(256 + c) * 128 + k - 128];
    vh[i] = f2bf(v);
}

// Gt[l][c][k] = gconv_w[l][k][c]
__global__ void k_prep_g(const float* __restrict__ gw, ushort_t* __restrict__ gh) {
    int i = blockIdx.x * 256 + threadIdx.x;   // l*16384 + c*128 + k, 128 blocks
    int l = i >> 14, r = i & 16383, c = r >> 7, k = r & 127;
    gh[i] = f2bf(gw[l * 16384 + k * 128 + c]);
}

// ---------------- m = h @ gw (MFMA bf16) -> bf16 m ----------------
// 2048 waves; wave w: nodes (w>>1)*64..+63, cols (w&1)*64..+63
__global__ __launch_bounds__(256, 4) void k_mgemm(const ushort_t* __restrict__ gth,
        const ushort_t* __restrict__ xh, ushort_t* __restrict__ m) {
    int t = threadIdx.x;
    int lane = t & 63, q = t >> 6;
    int w = blockIdx.x * 4 + q;
    int n0 = (w >> 1) * 64;
    int c0 = (w & 1) * 64;
    int lr = lane & 31, lh = lane >> 5;
    f32x16 acc[2][2];
    #pragma unroll
    for (int nt = 0; nt < 2; ++nt)
        #pragma unroll
        for (int ct = 0; ct < 2; ++ct)
            #pragma unroll
            for (int r = 0; r < 16; ++r) acc[nt][ct][r] = 0.f;
    size_t rowA0 = (size_t)(n0 + lr) * 256 + 128;   // h region
    size_t rowA1 = rowA0 + 32 * 256;
    #pragma unroll
    for (int ks = 0; ks < 8; ++ks) {
        int kg = ks * 16 + lh * 8;
        bf16x8 ah0 = *reinterpret_cast<const bf16x8*>(xh + rowA0 + kg);
        bf16x8 ah1 = *reinterpret_cast<const bf16x8*>(xh + rowA1 + kg);
        #pragma unroll
        for (int ct = 0; ct < 2; ++ct) {
            bf16x8 bh = *reinterpret_cast<const bf16x8*>(gth + (c0 + ct * 32 + lr) * 128 + kg);
            acc[0][ct] = MFMA(ah0, bh, acc[0][ct]);
            acc[1][ct] = MFMA(ah1, bh, acc[1][ct]);
        }
    }
    #pragma unroll
    for (int nt = 0; nt < 2; ++nt)
        #pragma unroll
        for (int ct = 0; ct < 2; ++ct)
            #pragma unroll
            for (int r = 0; r < 16; ++r) {
                int row = (r & 3) + 8 * (r >> 2) + 4 * lh;
                m[(size_t)(n0 + nt * 32 + row) * 128 + c0 + ct * 32 + lr] = f2bf(acc[nt][ct][r]);
            }
}

// ---------------- agg[n] = sum ew * m[esrc] -> bf16 into xcat[:,0:128] ----------------
// one wave per node; lane owns channels 2*lane, 2*lane+1
__global__ __launch_bounds__(256) void k_gather(const ushort_t* __restrict__ m,
        const int* __restrict__ offs, const int* __restrict__ esrc,
        const float* __restrict__ ew, ushort_t* __restrict__ xh) {
    int n = blockIdx.x * 4 + (threadIdx.x >> 6);
    int lane = threadIdx.x & 63;
    int k0 = offs[n], k1 = offs[n + 1];
    float a0 = 0.f, a1 = 0.f;
    int k = k0;
    for (; k < k1 && (k & 3); ++k) {
        int s = esrc[k];
        float w = ew[k];
        ushort2 u = *reinterpret_cast<const ushort2*>(m + (size_t)s * HH + 2 * lane);
        a0 = fmaf(w, bf2f(u.x), a0);
        a1 = fmaf(w, bf2f(u.y), a1);
    }
    for (; k + 4 <= k1; k += 4) {
        int4 s4 = *reinterpret_cast<const int4*>(esrc + k);
        float4 w4 = *reinterpret_cast<const float4*>(ew + k);
        ushort2 u0 = *reinterpret_cast<const ushort2*>(m + (size_t)s4.x * HH + 2 * lane);
        ushort2 u1 = *reinterpret_cast<const ushort2*>(m + (size_t)s4.y * HH + 2 * lane);
        ushort2 u2 = *reinterpret_cast<const ushort2*>(m + (size_t)s4.z * HH + 2 * lane);
        ushort2 u3 = *reinterpret_cast<const ushort2*>(m + (size_t)s4.w * HH + 2 * lane);
        a0 = fmaf(w4.x, bf2f(u0.x), a0); a1 = fmaf(w4.x, bf2f(u0.y), a1);
        a0 = fmaf(w4.y, bf2f(u1.x), a0); a1 = fmaf(w4.y, bf2f(u1.y), a1);
        a0 = fmaf(w4.z, bf2f(u2.x), a0); a1 = fmaf(w4.z, bf2f(u2.y), a1);
        a0 = fmaf(w4.w, bf2f(u3.x), a0); a1 = fmaf(w4.w, bf2f(u3.y), a1);
    }
    for (; k < k1; ++k) {
        int s = esrc[k];
        float w = ew[k];
        ushort2 u = *reinterpret_cast<const ushort2*>(m + (size_t)s * HH + 2 * lane);
        a0 = fmaf(w, bf2f(u.x), a0);
        a1 = fmaf(w, bf2f(u.y), a1);
    }
    ushort2 o; o.x = f2bf(a0); o.y = f2bf(a1);
    *reinterpret_cast<ushort2*>(xh + (size_t)n * 256 + 2 * lane) = o;
}

// ---------------- fused GRU via one K=256 MFMA GEMM (bf16, LDS-free) ----------------
// wave q: 64 nodes x V-rows q*128..+127 (4 gate tiles of 32 channels)
__global__ __launch_bounds__(256, 2) void k_gru(const ushort_t* __restrict__ vh,
        ushort_t* __restrict__ xh,
        const float* __restrict__ bih, const float* __restrict__ bhh) {
    int t = threadIdx.x;
    int lane = t & 63, q = t >> 6;
    int lr = lane & 31, lh = lane >> 5;
    int n0 = blockIdx.x * 64;
    f32x16 acc[2][4];
    #pragma unroll
    for (int nt = 0; nt < 2; ++nt)
        #pragma unroll
        for (int g = 0; g < 4; ++g)
            #pragma unroll
            for (int r = 0; r < 16; ++r) acc[nt][g][r] = 0.f;

    size_t rowA0 = (size_t)(n0 + lr) * 256;
    size_t rowA1 = rowA0 + 32 * 256;
    #pragma unroll
    for (int ks = 0; ks < 16; ++ks) {
        int kg = ks * 16 + lh * 8;
        bf16x8 ah0 = *reinterpret_cast<const bf16x8*>(xh + rowA0 + kg);
        bf16x8 ah1 = *reinterpret_cast<const bf16x8*>(xh + rowA1 + kg);
        #pragma unroll
        for (int g = 0; g < 4; ++g) {
            bf16x8 bh = *reinterpret_cast<const bf16x8*>(vh + (q * 128 + g * 32 + lr) * 256 + kg);
            acc[0][g] = MFMA(ah0, bh, acc[0][g]);
            acc[1][g] = MFMA(ah1, bh, acc[1][g]);
        }
    }

    __syncthreads();   // all waves done reading h before in-place overwrite

    int c = q * 32 + lr;
    float brz = bih[c] + bhh[c];
    float bzz = bih[128 + c] + bhh[128 + c];
    float bin = bih[256 + c];
    float bhn = bhh[256 + c];
    #pragma unroll
    for (int nt = 0; nt < 2; ++nt) {
        #pragma unroll
        for (int r = 0; r < 16; ++r) {
            int node = n0 + nt * 32 + (r & 3) + 8 * (r >> 2) + 4 * lh;
            float rg = sigm(acc[nt][0][r] + brz);
            float zg = sigm(acc[nt][1][r] + bzz);
            float nn = tanh_fast(acc[nt][2][r] + bin + rg * (acc[nt][3][r] + bhn));
            size_t idx = (size_t)node * 256 + 128 + c;
            float hold = bf2f(xh[idx]);
            float hnew = (1.f - zg) * nn + zg * hold;
            xh[idx] = f2bf(hnew);
        }
    }
}

// ---------------- relu + rearrange + conv1d(stride2,k3) + relu ----------------
__global__ __launch_bounds__(64) void k_conv(const ushort_t* __restrict__ xh,
        const float* __restrict__ cw, const float* __restrict__ cb,
        float* __restrict__ co) {
    __shared__ float tile[16 * 128];
    __shared__ float w[48];
    int be = blockIdx.x;
    int b = be >> 5, e = be & 31;
    int t = threadIdx.x;
    if (t < 48) w[t] = cw[t];
    #pragma unroll
    for (int i = 0; i < 8; ++i) {
        int f = t + i * 64;             // 0..511 groups of 4 channels
        int g = f >> 5, c4 = f & 31;
        size_t idx = (size_t)(b * 512 + g * 32 + e) * 256 + 128 + c4 * 4;
        ushort4 vh4 = *reinterpret_cast<const ushort4*>(xh + idx);
        float* dst = tile + g * 128 + c4 * 4;
        dst[0] = fmaxf(bf2f(vh4.x), 0.f);
        dst[1] = fmaxf(bf2f(vh4.y), 0.f);
        dst[2] = fmaxf(bf2f(vh4.z), 0.f);
        dst[3] = fmaxf(bf2f(vh4.w), 0.f);
    }
    __syncthreads();
    if (t < 63) {
        float s = cb[0];
        #pragma unroll
        for (int g = 0; g < 16; ++g) {
            const float* p = tile + g * 128 + 2 * t;
            s = fmaf(p[0], w[g * 3 + 0], s);
            s = fmaf(p[1], w[g * 3 + 1], s);
            s = fmaf(p[2], w[g * 3 + 2], s);
        }
        co[b * 2016 + e * 63 + t] = fmaxf(s, 0.f);
    }
}

// ---------------- lin1 ----------------
__global__ __launch_bounds__(128) void k_lin1(const float* __restrict__ co,
        const float* __restrict__ w, const float* __restrict__ bias,
        float* __restrict__ fc1) {
    __shared__ float v[2016];
    int b = blockIdx.x, t = threadIdx.x;
    for (int i = t; i < 2016; i += 128) v[i] = co[b * 2016 + i];
    __syncthreads();
    float s = bias[t];
    const float* wr = w + t * 2016;
    for (int k = 0; k < 2016; k += 4) {
        float4 wv = *reinterpret_cast<const float4*>(wr + k);
        s = fmaf(wv.x, v[k + 0], s);
        s = fmaf(wv.y, v[k + 1], s);
        s = fmaf(wv.z, v[k + 2], s);
        s = fmaf(wv.w, v[k + 3], s);
    }
    fc1[b * 128 + t] = fmaxf(s, 0.f);
}

// ---------------- lin2 + softmax ----------------
__global__ __launch_bounds__(128) void k_lin2(const float* __restrict__ fc1,
        const float* __restrict__ w, const float* __restrict__ bias,
        float* __restrict__ out) {
    int b = threadIdx.x;
    float s0 = bias[0], s1 = bias[1], s2 = bias[2];
    const float* v = fc1 + b * 128;
    for (int k = 0; k < 128; ++k) {
        float x = v[k];
        s0 = fmaf(x, w[k], s0);
        s1 = fmaf(x, w[128 + k], s1);
        s2 = fmaf(x, w[256 + k], s2);
    }
    float mx = fmaxf(s0, fmaxf(s1, s2));
    float e0 = __expf(s0 - mx), e1 = __expf(s1 - mx), e2 = __expf(s2 - mx);
    float inv = 1.f / (e0 + e1 + e2);
    out[b * 3 + 0] = e0 * inv;
    out[b * 3 + 1] = e1 * inv;
    out[b * 3 + 2] = e2 * inv;
}

extern "C" void kernel_launch(void* const* d_in, const int* in_sizes, int n_in,
                              void* d_out, int out_size, void* d_ws, size_t ws_size,
                              hipStream_t stream) {
    const float* x   = (const float*)d_in[0];
    const int*   ei  = (const int*)d_in[1];
    const float* ea  = (const float*)d_in[2];
    const float* gw  = (const float*)d_in[4];
    const float* wih = (const float*)d_in[5];
    const float* whh = (const float*)d_in[6];
    const float* bih = (const float*)d_in[7];
    const float* bhh = (const float*)d_in[8];
    const float* cw  = (const float*)d_in[9];
    const float* cb  = (const float*)d_in[10];
    const float* l1w = (const float*)d_in[11];
    const float* l1b = (const float*)d_in[12];
    const float* l2w = (const float*)d_in[13];
    const float* l2b = (const float*)d_in[14];
    float* out = (float*)d_out;

    char* p = (char*)d_ws;
    ushort_t* xh  = (ushort_t*)p; p += (size_t)NN * 256 * 2;      // 33.5 MB
    ushort_t* vh  = (ushort_t*)p; p += 512 * 256 * 2;
    ushort_t* gth = (ushort_t*)p; p += 2 * 128 * 128 * 2;
    ushort_t* m   = (ushort_t*)p; p += (size_t)NN * HH * 2;       // 16.7 MB
    float* co  = (float*)p; p += (size_t)BSZ * 2016 * 4;
    float* fc1 = (float*)p; p += (size_t)BSZ * HH * 4;
    int* deg   = (int*)p; p += (size_t)NN * 4;
    int* offs  = (int*)p; p += (size_t)(NN + 1) * 4;
    int* cur   = (int*)p; p += (size_t)NN * 4;
    int* bsum  = (int*)p; p += 256 * 4;
    int* boff  = (int*)p; p += 256 * 4;
    int* esrc  = (int*)p; p += (size_t)NE * 4;
    float* ew  = (float*)p;

    const int* src = ei;
    const int* dst = ei + NE;

    k_prep_v<<<512, 256, 0, stream>>>(wih, whh, vh);
    k_prep_g<<<128, 256, 0, stream>>>(gw, gth);
    k_zero_int<<<NN / 256, 256, 0, stream>>>(deg, NN);
    k_hist<<<NE / 256, 256, 0, stream>>>(dst, deg);
    k_scan1<<<256, 256, 0, stream>>>(deg, bsum);
    k_scan2<<<1, 256, 0, stream>>>(bsum, boff, offs);
    k_scan3<<<256, 256, 0, stream>>>(deg, boff, offs, cur);
    k_scatter<<<NE / 256, 256, 0, stream>>>(src, dst, ea, cur, esrc, ew);
    k_init<<<(NN * 128) / 256, 256, 0, stream>>>(x, xh);

    for (int layer = 0; layer < 2; ++layer) {
        k_mgemm<<<512, 256, 0, stream>>>(gth + (size_t)layer * 16384, xh, m);
        k_gather<<<NN / 4, 256, 0, stream>>>(m, offs, esrc, ew, xh);
        k_gru<<<NN / 64, 256, 0, stream>>>(vh, xh, bih, bhh);
    }

    k_conv<<<BSZ * ELEC, 64, 0, stream>>>(xh, cw, cb, co);
    k_lin1<<<BSZ, 128, 0, stream>>>(co, l1w, l1b, fc1);
    k_lin2<<<1, 128, 0, stream>>>(fc1, l2w, l2b, out);
}